// Round 2
// baseline (181.397 us; speedup 1.0000x reference)
//
#include <hip/hip_runtime.h>

// Fused: h = emb[:, :256] @ W_enc + b_enc ; LayerNorm(h)*gamma+beta ; ReLU
// (topology branch of the reference is a provable no-op: pooled == embeddings)
//
// Round 2: bf16 MFMA (16x16x32). Two kernels:
//   pack_w:    W_enc f32 [256,512] -> bf16 packed [k8][n][8k] in d_ws (256 KB)
//   topo_mfma: 256 blocks x 256 thr; block = 64 rows x N=512 x K=256.
//              Wave owns 16 full rows -> LayerNorm entirely in-register.

typedef unsigned int uint32;
typedef __attribute__((ext_vector_type(8))) short bf16x8;   // 8 bf16 = 4 VGPR
typedef __attribute__((ext_vector_type(4))) float floatx4;  // MFMA C/D

constexpr int D  = 512;   // output width (N)
constexpr int K  = 256;   // reduction (Dh)
constexpr int MB = 64;    // rows per block
constexpr int NT = 32;    // 16-wide n-tiles
constexpr float EPS = 1e-5f;

#define AS_G __attribute__((address_space(1)))
#define AS_L __attribute__((address_space(3)))

__device__ inline uint32 pack_bf2(float a, float b) {
    uint32 ua = __float_as_uint(a);
    ua += 0x7FFFu + ((ua >> 16) & 1u);          // RNE
    uint32 ub = __float_as_uint(b);
    ub += 0x7FFFu + ((ub >> 16) & 1u);
    return (ua >> 16) | (ub & 0xFFFF0000u);
}

// W [k=256][n=512] f32 -> Wp bf16, linear index (k8*512 + n)*8 + j  (j = k%8)
__global__ __launch_bounds__(256) void pack_w(const float* __restrict__ W,
                                              uint32* __restrict__ Wp) {
    const int t  = blockIdx.x * 256 + threadIdx.x;   // 0..16383
    const int k8 = t >> 9;                           // 0..31
    const int n  = t & 511;
    uint32 r[4];
    #pragma unroll
    for (int jj = 0; jj < 4; ++jj) {
        float v0 = W[(k8 * 8 + 2 * jj)     * D + n];  // coalesced per jj
        float v1 = W[(k8 * 8 + 2 * jj + 1) * D + n];
        r[jj] = pack_bf2(v0, v1);
    }
    uint4 o; o.x = r[0]; o.y = r[1]; o.z = r[2]; o.w = r[3];
    ((uint4*)Wp)[t] = o;                             // coalesced dwordx4
}

__global__ __launch_bounds__(256, 2)
void topo_mfma(const float* __restrict__ emb,
               const uint32* __restrict__ Wp,
               const float* __restrict__ benc,
               const float* __restrict__ gamma,
               const float* __restrict__ beta,
               float* __restrict__ out)
{
    // A: 32 k8-slices, pitch 65*16 B (pad breaks 32-bank aliasing). 33280 B.
    __shared__ uint32 s_a[32 * 260];
    // B chunk: 4 k8-slices x 512 n x 16 B = 32 KB, exact copy of a Wp chunk.
    __shared__ uint32 s_b[4 * 512 * 4];

    const int t    = threadIdx.x;
    const int wv   = t >> 6;           // wave 0..3 -> rows wv*16..wv*16+15
    const int lane = t & 63;
    const int q    = lane >> 4;        // quad 0..3
    const int cl   = lane & 15;
    const long row0 = (long)blockIdx.x * MB;

    // ---- issue B chunk 0 (async global->LDS, width 16) ----
    {
        const char* gsrc = (const char*)Wp;
        #pragma unroll
        for (int i = 0; i < 8; ++i) {
            int off = (wv * 8 + i) * 1024 + lane * 16;
            __builtin_amdgcn_global_load_lds((const AS_G uint32*)(gsrc + off),
                                             (AS_L uint32*)(&s_b[(wv * 8 + i) * 256]),
                                             16, 0, 0);
        }
    }

    // ---- stage A: 64 rows x 256 cols f32 -> bf16 [k8][m][8k] ----
    #pragma unroll
    for (int p = 0; p < 8; ++p) {
        int m  = p * 8 + (t >> 5);     // 2 consecutive rows per wave-pass
        int k8 = t & 31;               // lanes cover a full 1 KB row-half
        const float4* src = (const float4*)(emb + (row0 + m) * D + k8 * 8);
        float4 f0 = src[0], f1 = src[1];
        uint4 o;
        o.x = pack_bf2(f0.x, f0.y); o.y = pack_bf2(f0.z, f0.w);
        o.z = pack_bf2(f1.x, f1.y); o.w = pack_bf2(f1.z, f1.w);
        *(uint4*)&s_a[k8 * 260 + m * 4] = o;   // 1040 B stride: conflict-free
    }
    __syncthreads();   // drains A ds_writes AND chunk-0 global_load_lds

    floatx4 acc[NT];
    #pragma unroll
    for (int i = 0; i < NT; ++i) acc[i] = (floatx4){0.f, 0.f, 0.f, 0.f};

    // ---- K loop: 8 chunks of 32 (one MFMA per n-tile per chunk) ----
    for (int ch = 0; ch < 8; ++ch) {
        if (ch) {
            __syncthreads();           // all waves done reading prev chunk
            const char* gsrc = (const char*)Wp + ch * 32768;
            #pragma unroll
            for (int i = 0; i < 8; ++i) {
                int off = (wv * 8 + i) * 1024 + lane * 16;
                __builtin_amdgcn_global_load_lds((const AS_G uint32*)(gsrc + off),
                                                 (AS_L uint32*)(&s_b[(wv * 8 + i) * 256]),
                                                 16, 0, 0);
            }
            __syncthreads();           // chunk visible
        }
        // A fragment: lane holds A[m=cl][k = q*8+j] for rows wv*16+cl
        bf16x8 af = *(const bf16x8*)&s_a[(ch * 4 + q) * 260 + (wv * 16 + cl) * 4];
        #pragma unroll 8
        for (int nt = 0; nt < NT; ++nt) {
            // B fragment: lane holds B[k=q*8+j][n = nt*16+cl]
            bf16x8 bf = *(const bf16x8*)&s_b[(q * 512 + nt * 16 + cl) * 4];
            acc[nt] = __builtin_amdgcn_mfma_f32_16x16x32_bf16(af, bf, acc[nt], 0, 0, 0);
        }
    }

    // ---- epilogue: bias + in-register LayerNorm + ReLU ----
    // C/D layout: col = nt*16 + cl, row_local = q*4 + reg  (m89-verified)
    float sum[4] = {0.f, 0.f, 0.f, 0.f}, sq[4] = {0.f, 0.f, 0.f, 0.f};
    #pragma unroll
    for (int nt = 0; nt < NT; ++nt) {
        float bv = benc[nt * 16 + cl];
        #pragma unroll
        for (int r = 0; r < 4; ++r) {
            float v = acc[nt][r] + bv;
            acc[nt][r] = v;
            sum[r] += v;
            sq[r] = fmaf(v, v, sq[r]);
        }
    }
    // reduce across the 16 lanes sharing q (xor 1,2,4,8 stays in-group)
    #pragma unroll
    for (int m = 1; m < 16; m <<= 1) {
        #pragma unroll
        for (int r = 0; r < 4; ++r) {
            sum[r] += __shfl_xor(sum[r], m, 64);
            sq[r]  += __shfl_xor(sq[r],  m, 64);
        }
    }
    float mu[4], inv[4];
    #pragma unroll
    for (int r = 0; r < 4; ++r) {
        mu[r] = sum[r] * (1.f / 512.f);
        float var = sq[r] * (1.f / 512.f) - mu[r] * mu[r];
        inv[r] = rsqrtf(var + EPS);
    }
    #pragma unroll
    for (int nt = 0; nt < NT; ++nt) {
        int c = nt * 16 + cl;
        float g = gamma[c], be = beta[c];
        float* op = out + (row0 + wv * 16 + q * 4) * D + c;
        #pragma unroll
        for (int r = 0; r < 4; ++r) {
            float v = (acc[nt][r] - mu[r]) * inv[r] * g + be;
            op[r * D] = fmaxf(v, 0.f);   // 64B-segment coalesced
        }
    }
}

extern "C" void kernel_launch(void* const* d_in, const int* in_sizes, int n_in,
                              void* d_out, int out_size, void* d_ws, size_t ws_size,
                              hipStream_t stream) {
    // inputs: embeddings, W_proj, b_proj, W_enc, b_enc, ln_gamma, ln_beta
    const float* emb   = (const float*)d_in[0];
    const float* Wenc  = (const float*)d_in[3];
    const float* benc  = (const float*)d_in[4];
    const float* gamma = (const float*)d_in[5];
    const float* beta  = (const float*)d_in[6];
    float* outp = (float*)d_out;
    uint32* Wp = (uint32*)d_ws;            // 256 KB packed bf16 W

    pack_w<<<64, 256, 0, stream>>>(Wenc, Wp);
    const int rows = in_sizes[0] / D;      // 16384
    topo_mfma<<<rows / MB, 256, 0, stream>>>(emb, Wp, benc, gamma, beta, outp);
}

// Round 3
// 102.042 us; speedup vs baseline: 1.7777x; 1.7777x over previous
//
#include <hip/hip_runtime.h>

// Fused: h = emb[:, :256] @ W_enc + b_enc ; LayerNorm(h)*gamma+beta ; ReLU
// (topology branch of the reference is a provable no-op: pooled == embeddings)
//
// Round 3: fix round-2 scratch spill (acc dynamically indexed due to partial
// unroll -> 320 MB phantom scratch traffic). Wave tile = 32 rows x 128 cols:
// acc[2][8] statically indexed, B fragment reused across 2 row-tiles.
// MB=32 -> 512 blocks, ~50 KB LDS -> 2+ blocks/CU. Cross-wave LN via 1 KB LDS.

typedef unsigned int uint32;
typedef __attribute__((ext_vector_type(8))) short bf16x8;   // 8 bf16 = 4 VGPR
typedef __attribute__((ext_vector_type(4))) float floatx4;  // MFMA C/D

constexpr int D  = 512;   // output width (N)
constexpr int MB = 32;    // rows per block
constexpr float EPS = 1e-5f;

#define AS_G __attribute__((address_space(1)))
#define AS_L __attribute__((address_space(3)))

__device__ inline uint32 pack_bf2(float a, float b) {
    uint32 ua = __float_as_uint(a);
    ua += 0x7FFFu + ((ua >> 16) & 1u);          // RNE
    uint32 ub = __float_as_uint(b);
    ub += 0x7FFFu + ((ub >> 16) & 1u);
    return (ua >> 16) | (ub & 0xFFFF0000u);
}

// W [k=256][n=512] f32 -> Wp bf16, linear index (k8*512 + n)*8 + j  (j = k%8)
__global__ __launch_bounds__(256) void pack_w(const float* __restrict__ W,
                                              uint32* __restrict__ Wp) {
    const int t  = blockIdx.x * 256 + threadIdx.x;   // 0..16383
    const int k8 = t >> 9;                           // 0..31
    const int n  = t & 511;
    uint32 r[4];
    #pragma unroll
    for (int jj = 0; jj < 4; ++jj) {
        float v0 = W[(k8 * 8 + 2 * jj)     * D + n];
        float v1 = W[(k8 * 8 + 2 * jj + 1) * D + n];
        r[jj] = pack_bf2(v0, v1);
    }
    uint4 o; o.x = r[0]; o.y = r[1]; o.z = r[2]; o.w = r[3];
    ((uint4*)Wp)[t] = o;
}

__global__ __launch_bounds__(256, 2)
void topo_mfma(const float* __restrict__ emb,
               const uint32* __restrict__ Wp,
               const float* __restrict__ benc,
               const float* __restrict__ gamma,
               const float* __restrict__ beta,
               float* __restrict__ out)
{
    // A: 32 k8-slices x 32 rows x 16 B, pitch 132 dwords (528 B: 4-bank stagger)
    __shared__ uint32 s_a[32 * 132];            // 16.5 KB
    // B chunk: 4 k8-slices x 512 n x 16 B = 32 KB, contiguous (global_load_lds)
    __shared__ uint32 s_b[4 * 512 * 4];
    __shared__ float2 s_red[4][MB];             // per-wave row partial (sum, sumsq)

    const int t    = threadIdx.x;
    const int wv   = t >> 6;           // wave 0..3 -> cols wv*128 .. wv*128+127
    const int lane = t & 63;
    const int q    = lane >> 4;        // quad 0..3
    const int cl   = lane & 15;
    const long row0 = (long)blockIdx.x * MB;
    const char* gB = (const char*)Wp;

    // ---- issue B chunk 0 (async global->LDS, width 16) ----
    #pragma unroll
    for (int i = 0; i < 8; ++i) {
        int sl = wv * 8 + i;
        __builtin_amdgcn_global_load_lds((const AS_G uint32*)(gB + sl * 1024 + lane * 16),
                                         (AS_L uint32*)&s_b[sl * 256], 16, 0, 0);
    }

    // ---- stage A: 32 rows x 256 cols f32 -> bf16 [k8][m][8k] ----
    #pragma unroll
    for (int p = 0; p < 4; ++p) {
        int m  = p * 8 + (t >> 5);
        int k8 = t & 31;
        const float4* src = (const float4*)(emb + (row0 + m) * D + k8 * 8);
        float4 f0 = src[0], f1 = src[1];
        uint4 o;
        o.x = pack_bf2(f0.x, f0.y); o.y = pack_bf2(f0.z, f0.w);
        o.z = pack_bf2(f1.x, f1.y); o.w = pack_bf2(f1.z, f1.w);
        *(uint4*)&s_a[k8 * 132 + m * 4] = o;
    }
    __syncthreads();   // drains A ds_writes AND chunk-0 global_load_lds

    floatx4 acc[2][8];                // 64 regs/lane, ALL indices static
    #pragma unroll
    for (int rt = 0; rt < 2; ++rt)
        #pragma unroll
        for (int n2 = 0; n2 < 8; ++n2)
            acc[rt][n2] = (floatx4){0.f, 0.f, 0.f, 0.f};

    // ---- K loop: 8 chunks of k=32; B frag reused across 2 row-tiles ----
    for (int ch = 0; ch < 8; ++ch) {
        if (ch) {
            __syncthreads();           // all waves done reading prev chunk
            const char* g = gB + ch * 32768;
            #pragma unroll
            for (int i = 0; i < 8; ++i) {
                int sl = wv * 8 + i;
                __builtin_amdgcn_global_load_lds((const AS_G uint32*)(g + sl * 1024 + lane * 16),
                                                 (AS_L uint32*)&s_b[sl * 256], 16, 0, 0);
            }
            __syncthreads();           // chunk visible
        }
        // A frags: lane holds A[m = rt*16+cl][k = q*8+j]
        bf16x8 af0 = *(const bf16x8*)&s_a[(ch * 4 + q) * 132 + (cl) * 4];
        bf16x8 af1 = *(const bf16x8*)&s_a[(ch * 4 + q) * 132 + (16 + cl) * 4];
        #pragma unroll
        for (int n2 = 0; n2 < 8; ++n2) {
            // B frag: lane holds B[k = q*8+j][n = (wv*8+n2)*16 + cl]
            bf16x8 bf = *(const bf16x8*)&s_b[(q * 512 + (wv * 8 + n2) * 16 + cl) * 4];
            acc[0][n2] = __builtin_amdgcn_mfma_f32_16x16x32_bf16(af0, bf, acc[0][n2], 0, 0, 0);
            acc[1][n2] = __builtin_amdgcn_mfma_f32_16x16x32_bf16(af1, bf, acc[1][n2], 0, 0, 0);
        }
    }

    // ---- epilogue: bias + cross-wave LayerNorm + ReLU ----
    // C/D layout: col = (wv*8+n2)*16 + cl, row_local = rt*16 + q*4 + reg
    float bv[8], sum[2][4], sq[2][4];
    #pragma unroll
    for (int n2 = 0; n2 < 8; ++n2) bv[n2] = benc[(wv * 8 + n2) * 16 + cl];
    #pragma unroll
    for (int rt = 0; rt < 2; ++rt)
        #pragma unroll
        for (int r = 0; r < 4; ++r) { sum[rt][r] = 0.f; sq[rt][r] = 0.f; }

    #pragma unroll
    for (int n2 = 0; n2 < 8; ++n2)
        #pragma unroll
        for (int rt = 0; rt < 2; ++rt)
            #pragma unroll
            for (int r = 0; r < 4; ++r) {
                float v = acc[rt][n2][r] + bv[n2];
                acc[rt][n2][r] = v;
                sum[rt][r] += v;
                sq[rt][r] = fmaf(v, v, sq[rt][r]);
            }
    // reduce across the 16 cl-lanes (xor 1,2,4,8 stays within the quad group)
    #pragma unroll
    for (int m = 1; m < 16; m <<= 1)
        #pragma unroll
        for (int rt = 0; rt < 2; ++rt)
            #pragma unroll
            for (int r = 0; r < 4; ++r) {
                sum[rt][r] += __shfl_xor(sum[rt][r], m, 64);
                sq[rt][r]  += __shfl_xor(sq[rt][r],  m, 64);
            }
    if (cl == 0) {
        #pragma unroll
        for (int rt = 0; rt < 2; ++rt)
            #pragma unroll
            for (int r = 0; r < 4; ++r)
                s_red[wv][rt * 16 + q * 4 + r] = make_float2(sum[rt][r], sq[rt][r]);
    }
    __syncthreads();

    float mu[2][4], inv[2][4];
    #pragma unroll
    for (int rt = 0; rt < 2; ++rt)
        #pragma unroll
        for (int r = 0; r < 4; ++r) {
            int row = rt * 16 + q * 4 + r;
            float s = 0.f, ss = 0.f;
            #pragma unroll
            for (int w = 0; w < 4; ++w) {
                float2 v = s_red[w][row];
                s += v.x; ss += v.y;
            }
            float m_ = s * (1.f / 512.f);
            float var = ss * (1.f / 512.f) - m_ * m_;
            mu[rt][r] = m_;
            inv[rt][r] = rsqrtf(var + EPS);
        }

    #pragma unroll
    for (int n2 = 0; n2 < 8; ++n2) {
        int c = (wv * 8 + n2) * 16 + cl;
        float g = gamma[c], be = beta[c];
        #pragma unroll
        for (int rt = 0; rt < 2; ++rt) {
            float* op = out + (row0 + rt * 16 + q * 4) * D + c;
            #pragma unroll
            for (int r = 0; r < 4; ++r) {
                float v = (acc[rt][n2][r] - mu[rt][r]) * inv[rt][r] * g + be;
                op[r * D] = fmaxf(v, 0.f);
            }
        }
    }
}

extern "C" void kernel_launch(void* const* d_in, const int* in_sizes, int n_in,
                              void* d_out, int out_size, void* d_ws, size_t ws_size,
                              hipStream_t stream) {
    // inputs: embeddings, W_proj, b_proj, W_enc, b_enc, ln_gamma, ln_beta
    const float* emb   = (const float*)d_in[0];
    const float* Wenc  = (const float*)d_in[3];
    const float* benc  = (const float*)d_in[4];
    const float* gamma = (const float*)d_in[5];
    const float* beta  = (const float*)d_in[6];
    float* outp = (float*)d_out;
    uint32* Wp = (uint32*)d_ws;            // 256 KB packed bf16 W

    pack_w<<<64, 256, 0, stream>>>(Wenc, Wp);
    const int rows = in_sizes[0] / D;      // 16384
    topo_mfma<<<rows / MB, 256, 0, stream>>>(emb, Wp, benc, gamma, beta, outp);
}